// Round 8
// baseline (117.141 us; speedup 1.0000x reference)
//
#include <hip/hip_runtime.h>

// 3 kernels:
//  k_dot   (500 blk): V = h @ W_top, MA = bitmask(g)           [HBM-bound]
//  k_top2  (50 blk):  SH(+out[0:500]) + scores + rank top-400 + dense 2-hop
//                     on sparse g -> CP rows / RSUM / SU        [parallel]
//  k_layers(1 blk):   all 4 pooling layers entirely in LDS      [latency]
// Complement representation: pooled 2-hop graphs are ~99.5% dense, so per-row
// COMPLEMENT masks CP (~2-3 bits) make matvecs (total - complement) and
// next 2-hops (intersect of complements, early exit) nearly free.
// ws (u32 words): V@0, SELA@512(16), IDXA@544, CPg@1056(8000), RSUMo@9056,
// SUc@9568, MA@10080(8000)

#define MS 16

__device__ __forceinline__ float fbfly(float v) {
#pragma unroll
    for (int o = 32; o; o >>= 1) v += __shfl_xor(v, o);
    return v;
}
__device__ __forceinline__ int ibfly(int v) {
#pragma unroll
    for (int o = 32; o; o >>= 1) v += __shfl_xor(v, o);
    return v;
}

// sparse bit-walk dot over a full 16-word row (LDS resident)
__device__ __forceinline__ float pwalk16(const unsigned* __restrict__ row,
                                         const float* __restrict__ val) {
    float a = 0.f;
#pragma unroll
    for (int w = 0; w < 16; ++w) {
        unsigned m = row[w];
        while (m) {
            int b = __ffs((int)m) - 1;
            m &= m - 1;
            a += val[(w << 5) + b];
        }
    }
    return a;
}

// stable rank of (my, idx) among 512 LDS scores (pads hold -1)
__device__ __forceinline__ int rank512(const float* __restrict__ sc, float my,
                                       int idx) {
    int c0 = 0, c1 = 0, c2 = 0, c3 = 0;
    for (int j = 0; j < 512; j += 4) {
        float4 v = *(const float4*)(sc + j);
        c0 += (v.x > my) || (v.x == my && (j + 0) < idx);
        c1 += (v.y > my) || (v.y == my && (j + 1) < idx);
        c2 += (v.z > my) || (v.z == my && (j + 2) < idx);
        c3 += (v.w > my) || (v.w == my && (j + 3) < idx);
    }
    return (c0 + c1) + (c2 + c3);
}

// V[row] = dot(h[row,:], W_top); MA[row] = bitmask of g row.
__global__ __launch_bounds__(1024) void k_dot(const float* __restrict__ h,
        const float* __restrict__ Wt, const float* __restrict__ g,
        float* __restrict__ V, unsigned* __restrict__ MA) {
    int row = blockIdx.x, t = threadIdx.x;
    const float4* h4 = (const float4*)(h + (size_t)row * 32768);
    const float4* w4 = (const float4*)Wt;
    float acc = 0.f;
#pragma unroll
    for (int j = 0; j < 8; ++j) {
        float4 a = h4[t + 1024 * j], b = w4[t + 1024 * j];
        acc = fmaf(a.x, b.x, fmaf(a.y, b.y, fmaf(a.z, b.z, fmaf(a.w, b.w, acc))));
    }
    acc = fbfly(acc);
    __shared__ float red[16];
    if ((t & 63) == 0) red[t >> 6] = acc;
    __syncthreads();
    if (t == 0) {
        float s = 0.f;
        for (int i = 0; i < 16; ++i) s += red[i];
        V[row] = s;
    }
    if (t < 512) {
        float gv = (t < 500) ? g[row * 500 + t] : 0.f;
        unsigned long long bal = __ballot(gv != 0.f);
        if ((t & 63) == 0) {
            int w = t >> 6;
            MA[row * MS + 2 * w] = (unsigned)bal;
            MA[row * MS + 2 * w + 1] = (unsigned)(bal >> 32);
        }
    }
}

// Fused: SH + out[0:500], z-scores, stable top-400 rank, dense layer-0 twohop.
// Cheap phases redundant per block (identical deterministic results); the
// heavy 2-hop column scan is distributed: wave per selected row, 8/block.
__global__ __launch_bounds__(512) void k_top2(const unsigned* __restrict__ MA,
        const float* __restrict__ V, const float* __restrict__ b_top,
        const float* __restrict__ Wp0, const float* __restrict__ bp0,
        const float* __restrict__ Wd0, float* __restrict__ out,
        unsigned* __restrict__ SELA, int* __restrict__ IDXA,
        unsigned* __restrict__ CPg, float* __restrict__ RSUMo,
        float* __restrict__ SUc) {
    __shared__ unsigned sMA[8000];
    __shared__ __align__(16) float sv[512], sh[512], sz[512];
    __shared__ unsigned sSEL[16];
    __shared__ int sIDX[512];
    int t = threadIdx.x;
    for (int q = t; q < 8000; q += 512) sMA[q] = MA[q];
    sv[t] = (t < 500) ? V[t] : 0.f;
    if (t < 16) sSEL[t] = 0u;
    __syncthreads();
    float shv = 0.f;
    if (t < 500) {
        float a = pwalk16(sMA + t * MS, sv);
        shv = fmaxf(a + b_top[0], 0.f);
    }
    sh[t] = (t < 500) ? shv : 0.f;
    __syncthreads();
    if (blockIdx.x == 0 && t < 500) out[t] = shv;
    float z = -1.f;
    if (t < 500) {
        float a = pwalk16(sMA + t * MS, sh);
        z = fmaxf(a * Wp0[0] + bp0[0], 0.f);  // sigmoid monotone: rank on z
    }
    sz[t] = z;
    __syncthreads();
    if (t < 500) {
        int cnt = rank512(sz, z, t);
        if (cnt < 400) {
            sIDX[cnt] = t;
            atomicOr(&sSEL[t >> 5], 1u << (t & 31));
        }
    }
    __syncthreads();
    if (blockIdx.x == 0) {
        if (t < 16) SELA[t] = sSEL[t];
        if (t < 400) IDXA[t] = sIDX[t];
    }
    // dense twohop over sparse g, wave per selected row
    int wid = t >> 6, lane = t & 63;
    int r4 = blockIdx.x * 8 + wid;
    if (r4 < 400) {
        int i = sIDX[r4];
        int part = lane >> 4, w = lane & 15;
        unsigned acc = 0;
        for (int k = part; k < 500; k += 4) {
            unsigned sel = (sMA[i * MS + (k >> 5)] >> (k & 31)) & 1u;
            acc |= sMA[k * MS + w] & (0u - sel);
        }
        acc |= (unsigned)__shfl_xor((int)acc, 16);
        acc |= (unsigned)__shfl_xor((int)acc, 32);
        unsigned P = sSEL[w] & ~acc;  // complement within selection
        int pcl = (lane < 16) ? __popc(P) : 0;
        pcl = ibfly(pcl);
        if (lane < 16) CPg[i * MS + lane] = P;
        if (lane == 0) {
            float rs = (float)(400 - pcl);
            RSUMo[i] = rs;
            float sc = 1.f / (1.f + expf(-sz[i]));
            SUc[r4] = sh[i] * sc * Wd0[r4] / rs;
        }
    }
}

struct P4 { const float* p[4]; };

// All 4 pooling layers in one block, fully LDS-resident.
__global__ __launch_bounds__(1024) void k_layers(const unsigned* __restrict__ SELA,
        const int* __restrict__ IDXA, const unsigned* __restrict__ CPg,
        const float* __restrict__ RSUMg, const float* __restrict__ SUg,
        P4 Wp, P4 bp, P4 Wd, P4 bd, float* __restrict__ out) {
    __shared__ unsigned sCP[8000];
    __shared__ __align__(16) float svC[512], s2C[512], szC[512];
    __shared__ float svO[512], s2O[512], shvO[512], sHSo[512], srsO[512];
    __shared__ unsigned sSEL[2][16];
    __shared__ int sIDX[2][512];
    __shared__ float stot;
    int t = threadIdx.x;
    if (t < 512) {
        svC[t] = (t < 400) ? SUg[t] : 0.f;
        sIDX[0][t] = (t < 400) ? IDXA[t] : 0;
    }
    if (t < 16) sSEL[0][t] = SELA[t];
    __syncthreads();
    if (t < 400) {
        int i = sIDX[0][t];
        svO[i] = svC[t];
        srsO[i] = RSUMg[i];
    }
    for (int q = t; q < 6400; q += 1024) {
        int c = q >> 4, w = q & 15;
        int i = sIDX[0][c];
        sCP[i * MS + w] = CPg[i * MS + w];
    }
    __syncthreads();

    const int kks[4] = {400, 300, 200, 100};
    const int kns[4] = {300, 200, 100, 0};
    const int offs[4] = {500, 900, 1200, 1400};
#pragma unroll
    for (int l = 0; l < 4; ++l) {
        const int kk = kks[l], knext = kns[l], off = offs[l];
        const int cur = l & 1, nxt = cur ^ 1;
        // total(su) fixed tree
        if (t < 64) {
            float p = 0.f;
#pragma unroll
            for (int j = 0; j < 8; ++j) p += svC[t * 8 + j];
            p = fbfly(p);
            if (t == 0) stot = p;
        }
        __syncthreads();
        // mid0: down-GCN = total - complement
        int i_ = 0;
        if (t < kk) {
            i_ = sIDX[cur][t];
            float corr = pwalk16(sCP + i_ * MS, svO);
            float hv = fmaxf(stot - corr + bd.p[l][0], 0.f);
            out[off + t] = hv;
            shvO[i_] = hv;
            float s2 = hv / srsO[i_];
            s2C[t] = s2;
            s2O[i_] = s2;
        } else if (t < 512) {
            s2C[t] = 0.f;
        }
        if (l == 3) break;
        __syncthreads();
        // total(su2)
        if (t < 64) {
            float p = 0.f;
#pragma unroll
            for (int j = 0; j < 8; ++j) p += s2C[t * 8 + j];
            p = fbfly(p);
            if (t == 0) stot = p;
        }
        if (t < 16) sSEL[nxt][t] = 0u;
        __syncthreads();
        // mid1: z scores (sigmoid monotone -> rank on z)
        float z_ = -1.f;
        if (t < kk) {
            float c2 = pwalk16(sCP + i_ * MS, s2O);
            z_ = fmaxf((stot - c2) * Wp.p[l + 1][0] + bp.p[l + 1][0], 0.f);
        }
        if (t < 512) szC[t] = (t < kk) ? z_ : -1.f;
        __syncthreads();
        // rank top-knext (stable, compact-index tie-break)
        if (t < kk) {
            int cnt = rank512(szC, z_, t);
            if (cnt < knext) {
                sIDX[nxt][cnt] = i_;
                sHSo[i_] = shvO[i_] * (1.f / (1.f + expf(-z_)));
                atomicOr(&sSEL[nxt][i_ >> 5], 1u << (i_ & 31));
            }
        }
        __syncthreads();
        // hop: newCP[i] = SELn & intersect CP[j] over current nbrs, early exit
        unsigned P[16];
        int inew = 0, pc = 0;
        float su_ = 0.f;
        if (t < knext) {
            inew = sIDX[nxt][t];
#pragma unroll
            for (int w = 0; w < 16; ++w) P[w] = sSEL[nxt][w];
            bool alive = true;
            for (int w2 = 0; w2 < 16 && alive; ++w2) {
                unsigned nb = sSEL[cur][w2] & ~sCP[inew * MS + w2];
                while (nb) {
                    int b = __ffs((int)nb) - 1;
                    nb &= nb - 1;
                    const unsigned* cj = sCP + (w2 * 32 + b) * MS;
                    unsigned orr = 0;
#pragma unroll
                    for (int w = 0; w < 16; ++w) {
                        P[w] &= cj[w];
                        orr |= P[w];
                    }
                    if (!orr) { alive = false; break; }
                }
            }
#pragma unroll
            for (int w = 0; w < 16; ++w) pc += __popc(P[w]);
            float rs = (float)(knext - pc);
            su_ = sHSo[inew] * Wd.p[l + 1][t] / rs;
        }
        __syncthreads();  // all sCP reads done -> safe to overwrite rows
        if (t < knext) {
#pragma unroll
            for (int w = 0; w < 16; ++w) sCP[inew * MS + w] = P[w];
            srsO[inew] = (float)(knext - pc);
            svC[t] = su_;
            svO[inew] = su_;
        } else if (t < 512) {
            svC[t] = 0.f;
        }
        __syncthreads();
    }
}

extern "C" void kernel_launch(void* const* d_in, const int* in_sizes, int n_in,
                              void* d_out, int out_size, void* d_ws, size_t ws_size,
                              hipStream_t stream) {
    const float* g = (const float*)d_in[0];
    const float* h = (const float*)d_in[1];
    const float* W_top = (const float*)d_in[2];
    const float* b_top = (const float*)d_in[3];
    P4 Wp, bp, Wd, bd;
    for (int i = 0; i < 4; ++i) {
        Wp.p[i] = (const float*)d_in[4 + 4 * i];
        bp.p[i] = (const float*)d_in[5 + 4 * i];
        Wd.p[i] = (const float*)d_in[6 + 4 * i];
        bd.p[i] = (const float*)d_in[7 + 4 * i];
    }
    float* out = (float*)d_out;

    unsigned* wsu = (unsigned*)d_ws;
    float* V = (float*)(wsu + 0);
    unsigned* SELA = wsu + 512;
    int* IDXA = (int*)(wsu + 544);
    unsigned* CPg = wsu + 1056;
    float* RSUMo = (float*)(wsu + 9056);
    float* SUc = (float*)(wsu + 9568);
    unsigned* MA = wsu + 10080;

    k_dot<<<500, 1024, 0, stream>>>(h, W_top, g, V, MA);
    k_top2<<<50, 512, 0, stream>>>(MA, V, b_top, Wp.p[0], bp.p[0], Wd.p[0], out,
                                   SELA, IDXA, CPg, RSUMo, SUc);
    k_layers<<<1, 1024, 0, stream>>>(SELA, IDXA, CPg, RSUMo, SUc, Wp, bp, Wd, bd,
                                     out);
}

// Round 9
// 115.944 us; speedup vs baseline: 1.0103x; 1.0103x over previous
//
#include <hip/hip_runtime.h>

// 3 kernels:
//  k_dot   (500 blk): V = h @ W_top, MA = bitmask(g)           [HBM-bound]
//  k_top2  (50 blk):  SH(+out[0:500]) + scores + rank top-400 + dense 2-hop
//                     on sparse g -> CP rows / RSUM / SU        [parallel]
//  k_layers(1 blk):   all 4 pooling layers entirely in LDS      [latency]
// Complement representation: pooled 2-hop graphs are ~99.5% dense, so per-row
// COMPLEMENT masks CP (~2-3 bits) make matvecs (total - complement) and
// next 2-hops (intersect of complements, early exit) nearly free.
// Rank is wave-cooperative: 1 wave/row, lane-strided float4 scan + butterfly.
// ws (u32 words): V@0, SELA@512(16), IDXA@544, CPg@1056(8000), RSUMo@9056,
// SUc@9568, MA@10080(8000)

#define MS 16

__device__ __forceinline__ float fbfly(float v) {
#pragma unroll
    for (int o = 32; o; o >>= 1) v += __shfl_xor(v, o);
    return v;
}
__device__ __forceinline__ int ibfly(int v) {
#pragma unroll
    for (int o = 32; o; o >>= 1) v += __shfl_xor(v, o);
    return v;
}

// sparse bit-walk dot over a full 16-word row (LDS resident)
__device__ __forceinline__ float pwalk16(const unsigned* __restrict__ row,
                                         const float* __restrict__ val) {
    float a = 0.f;
#pragma unroll
    for (int w = 0; w < 16; ++w) {
        unsigned m = row[w];
        while (m) {
            int b = __ffs((int)m) - 1;
            m &= m - 1;
        a += val[(w << 5) + b];
        }
    }
    return a;
}

// wave-cooperative stable-rank body: count over the padded 512-float array
// (pads = -1 < any score). lane covers float4s {lane, lane+64}.
__device__ __forceinline__ int wrank(const float* __restrict__ sc, float my,
                                     int r, int lane) {
    int cnt = 0;
#pragma unroll
    for (int q = 0; q < 2; ++q) {
        int j = (lane + 64 * q) << 2;
        float4 v = *(const float4*)(sc + j);
        cnt += (v.x > my) || (v.x == my && (j + 0) < r);
        cnt += (v.y > my) || (v.y == my && (j + 1) < r);
        cnt += (v.z > my) || (v.z == my && (j + 2) < r);
        cnt += (v.w > my) || (v.w == my && (j + 3) < r);
    }
    return ibfly(cnt);
}

// V[row] = dot(h[row,:], W_top); MA[row] = bitmask of g row.
__global__ __launch_bounds__(1024) void k_dot(const float* __restrict__ h,
        const float* __restrict__ Wt, const float* __restrict__ g,
        float* __restrict__ V, unsigned* __restrict__ MA) {
    int row = blockIdx.x, t = threadIdx.x;
    const float4* h4 = (const float4*)(h + (size_t)row * 32768);
    const float4* w4 = (const float4*)Wt;
    float acc = 0.f;
#pragma unroll
    for (int j = 0; j < 8; ++j) {
        float4 a = h4[t + 1024 * j], b = w4[t + 1024 * j];
        acc = fmaf(a.x, b.x, fmaf(a.y, b.y, fmaf(a.z, b.z, fmaf(a.w, b.w, acc))));
    }
    acc = fbfly(acc);
    __shared__ float red[16];
    if ((t & 63) == 0) red[t >> 6] = acc;
    __syncthreads();
    if (t == 0) {
        float s = 0.f;
        for (int i = 0; i < 16; ++i) s += red[i];
        V[row] = s;
    }
    if (t < 512) {
        float gv = (t < 500) ? g[row * 500 + t] : 0.f;
        unsigned long long bal = __ballot(gv != 0.f);
        if ((t & 63) == 0) {
            int w = t >> 6;
            MA[row * MS + 2 * w] = (unsigned)bal;
            MA[row * MS + 2 * w + 1] = (unsigned)(bal >> 32);
        }
    }
}

// Fused: SH + out[0:500], z-scores, stable top-400 rank, dense layer-0 twohop.
__global__ __launch_bounds__(512) void k_top2(const unsigned* __restrict__ MA,
        const float* __restrict__ V, const float* __restrict__ b_top,
        const float* __restrict__ Wp0, const float* __restrict__ bp0,
        const float* __restrict__ Wd0, float* __restrict__ out,
        unsigned* __restrict__ SELA, int* __restrict__ IDXA,
        unsigned* __restrict__ CPg, float* __restrict__ RSUMo,
        float* __restrict__ SUc) {
    __shared__ unsigned sMA[8000];
    __shared__ __align__(16) float sv[512], sh[512], sz[512];
    __shared__ unsigned sSEL[16];
    __shared__ int sIDX[512];
    int t = threadIdx.x;
    int wid = t >> 6, lane = t & 63;
    for (int q = t; q < 8000; q += 512) sMA[q] = MA[q];
    sv[t] = (t < 500) ? V[t] : 0.f;
    if (t < 16) sSEL[t] = 0u;
    __syncthreads();
    float shv = 0.f;
    if (t < 500) {
        float a = pwalk16(sMA + t * MS, sv);
        shv = fmaxf(a + b_top[0], 0.f);
    }
    sh[t] = (t < 500) ? shv : 0.f;
    __syncthreads();
    if (blockIdx.x == 0 && t < 500) out[t] = shv;
    float z = -1.f;
    if (t < 500) {
        float a = pwalk16(sMA + t * MS, sh);
        z = fmaxf(a * Wp0[0] + bp0[0], 0.f);  // sigmoid monotone: rank on z
    }
    sz[t] = z;
    __syncthreads();
    // cooperative rank: wave per row
    for (int r = wid; r < 500; r += 8) {
        float my = sz[r];
        int cnt = wrank(sz, my, r, lane);
        if (lane == 0 && cnt < 400) {
            sIDX[cnt] = r;
            atomicOr(&sSEL[r >> 5], 1u << (r & 31));
        }
    }
    __syncthreads();
    if (blockIdx.x == 0) {
        if (t < 16) SELA[t] = sSEL[t];
        if (t < 400) IDXA[t] = sIDX[t];
    }
    // dense twohop over sparse g, wave per selected row
    int r4 = blockIdx.x * 8 + wid;
    if (r4 < 400) {
        int i = sIDX[r4];
        int part = lane >> 4, w = lane & 15;
        unsigned acc = 0;
        for (int k = part; k < 500; k += 4) {
            unsigned sel = (sMA[i * MS + (k >> 5)] >> (k & 31)) & 1u;
            acc |= sMA[k * MS + w] & (0u - sel);
        }
        acc |= (unsigned)__shfl_xor((int)acc, 16);
        acc |= (unsigned)__shfl_xor((int)acc, 32);
        unsigned P = sSEL[w] & ~acc;  // complement within selection
        int pcl = (lane < 16) ? __popc(P) : 0;
        pcl = ibfly(pcl);
        if (lane < 16) CPg[i * MS + lane] = P;
        if (lane == 0) {
            float rs = (float)(400 - pcl);
            RSUMo[i] = rs;
            float sc = 1.f / (1.f + expf(-sz[i]));
            SUc[r4] = sh[i] * sc * Wd0[r4] / rs;
        }
    }
}

struct P4 { const float* p[4]; };

// All 4 pooling layers in one block, fully LDS-resident.
__global__ __launch_bounds__(1024) void k_layers(const unsigned* __restrict__ SELA,
        const int* __restrict__ IDXA, const unsigned* __restrict__ CPg,
        const float* __restrict__ RSUMg, const float* __restrict__ SUg,
        P4 Wp, P4 bp, P4 Wd, P4 bd, float* __restrict__ out) {
    __shared__ unsigned sCP[8000];
    __shared__ __align__(16) float svC[512], s2C[512], szC[512];
    __shared__ float svO[512], s2O[512], shvO[512], sHSo[512], srsO[512];
    __shared__ unsigned sSEL[2][16];
    __shared__ int sIDX[2][512];
    __shared__ float stot;
    int t = threadIdx.x;
    int wid = t >> 6, lane = t & 63;
    if (t < 512) {
        svC[t] = (t < 400) ? SUg[t] : 0.f;
        sIDX[0][t] = (t < 400) ? IDXA[t] : 0;
    }
    if (t < 16) sSEL[0][t] = SELA[t];
    __syncthreads();
    if (t < 400) {
        int i = sIDX[0][t];
        svO[i] = svC[t];
        srsO[i] = RSUMg[i];
    }
    for (int q = t; q < 6400; q += 1024) {
        int c = q >> 4, w = q & 15;
        int i = sIDX[0][c];
        sCP[i * MS + w] = CPg[i * MS + w];
    }
    __syncthreads();

    const int kks[4] = {400, 300, 200, 100};
    const int kns[4] = {300, 200, 100, 0};
    const int offs[4] = {500, 900, 1200, 1400};
#pragma unroll
    for (int l = 0; l < 4; ++l) {
        const int kk = kks[l], knext = kns[l], off = offs[l];
        const int cur = l & 1, nxt = cur ^ 1;
        // total(su) fixed tree
        if (t < 64) {
            float p = 0.f;
#pragma unroll
            for (int j = 0; j < 8; ++j) p += svC[t * 8 + j];
            p = fbfly(p);
            if (t == 0) stot = p;
        }
        __syncthreads();
        // mid0: down-GCN = total - complement
        int i_ = 0;
        if (t < kk) {
            i_ = sIDX[cur][t];
            float corr = pwalk16(sCP + i_ * MS, svO);
            float hv = fmaxf(stot - corr + bd.p[l][0], 0.f);
            out[off + t] = hv;
            shvO[i_] = hv;
            float s2 = hv / srsO[i_];
            s2C[t] = s2;
            s2O[i_] = s2;
        } else if (t < 512) {
            s2C[t] = 0.f;
        }
        if (l == 3) break;
        __syncthreads();
        // total(su2)
        if (t < 64) {
            float p = 0.f;
#pragma unroll
            for (int j = 0; j < 8; ++j) p += s2C[t * 8 + j];
            p = fbfly(p);
            if (t == 0) stot = p;
        }
        if (t < 16) sSEL[nxt][t] = 0u;
        __syncthreads();
        // mid1: z scores (sigmoid monotone -> rank on z)
        float z_ = -1.f;
        if (t < kk) {
            float c2 = pwalk16(sCP + i_ * MS, s2O);
            z_ = fmaxf((stot - c2) * Wp.p[l + 1][0] + bp.p[l + 1][0], 0.f);
        }
        if (t < 512) szC[t] = (t < kk) ? z_ : -1.f;
        __syncthreads();
        // cooperative rank top-knext: wave per compact row
        for (int r = wid; r < kk; r += 16) {
            float my = szC[r];
            int cnt = wrank(szC, my, r, lane);
            if (lane == 0 && cnt < knext) {
                int io = sIDX[cur][r];
                sIDX[nxt][cnt] = io;
                sHSo[io] = shvO[io] * (1.f / (1.f + expf(-my)));
                atomicOr(&sSEL[nxt][io >> 5], 1u << (io & 31));
            }
        }
        __syncthreads();
        // hop: newCP[i] = SELn & intersect CP[j] over current nbrs, early exit
        unsigned P[16];
        int inew = 0, pc = 0;
        float su_ = 0.f;
        if (t < knext) {
            inew = sIDX[nxt][t];
#pragma unroll
            for (int w = 0; w < 16; ++w) P[w] = sSEL[nxt][w];
            bool alive = true;
            for (int w2 = 0; w2 < 16 && alive; ++w2) {
                unsigned nb = sSEL[cur][w2] & ~sCP[inew * MS + w2];
                while (nb) {
                    int b = __ffs((int)nb) - 1;
                    nb &= nb - 1;
                    const unsigned* cj = sCP + (w2 * 32 + b) * MS;
                    unsigned orr = 0;
#pragma unroll
                    for (int w = 0; w < 16; ++w) {
                        P[w] &= cj[w];
                        orr |= P[w];
                    }
                    if (!orr) { alive = false; break; }
                }
            }
#pragma unroll
            for (int w = 0; w < 16; ++w) pc += __popc(P[w]);
            float rs = (float)(knext - pc);
            su_ = sHSo[inew] * Wd.p[l + 1][t] / rs;
        }
        __syncthreads();  // all sCP reads done -> safe to overwrite rows
        if (t < knext) {
#pragma unroll
            for (int w = 0; w < 16; ++w) sCP[inew * MS + w] = P[w];
            srsO[inew] = (float)(knext - pc);
            svC[t] = su_;
            svO[inew] = su_;
        } else if (t < 512) {
            svC[t] = 0.f;
        }
        __syncthreads();
    }
}

extern "C" void kernel_launch(void* const* d_in, const int* in_sizes, int n_in,
                              void* d_out, int out_size, void* d_ws, size_t ws_size,
                              hipStream_t stream) {
    const float* g = (const float*)d_in[0];
    const float* h = (const float*)d_in[1];
    const float* W_top = (const float*)d_in[2];
    const float* b_top = (const float*)d_in[3];
    P4 Wp, bp, Wd, bd;
    for (int i = 0; i < 4; ++i) {
        Wp.p[i] = (const float*)d_in[4 + 4 * i];
        bp.p[i] = (const float*)d_in[5 + 4 * i];
        Wd.p[i] = (const float*)d_in[6 + 4 * i];
        bd.p[i] = (const float*)d_in[7 + 4 * i];
    }
    float* out = (float*)d_out;

    unsigned* wsu = (unsigned*)d_ws;
    float* V = (float*)(wsu + 0);
    unsigned* SELA = wsu + 512;
    int* IDXA = (int*)(wsu + 544);
    unsigned* CPg = wsu + 1056;
    float* RSUMo = (float*)(wsu + 9056);
    float* SUc = (float*)(wsu + 9568);
    unsigned* MA = wsu + 10080;

    k_dot<<<500, 1024, 0, stream>>>(h, W_top, g, V, MA);
    k_top2<<<50, 512, 0, stream>>>(MA, V, b_top, Wp.p[0], bp.p[0], Wd.p[0], out,
                                   SELA, IDXA, CPg, RSUMo, SUc);
    k_layers<<<1, 1024, 0, stream>>>(SELA, IDXA, CPg, RSUMo, SUc, Wp, bp, Wd, bd,
                                     out);
}

// Round 10
// 68.022 us; speedup vs baseline: 1.7221x; 1.7045x over previous
//
#include <hip/hip_runtime.h>

// 8 kernels, all heavy phases multi-block; layers 1-3 collapse to scalars when
// the layer-1 graph is complete (provable for ~2-3-bit CP0 rows; verified
// on-device via allEmpty flag, with a general fallback path).
// ws (u32 words): V@0, SHo@512, Z@1024, IDXA@1536, SELA@2048(32), HSo@2080,
// RSUMo@2592, SUc@3104, SUo@3616, H1c@4128, S2c@4640, S2o@5152, Z1c@5664,
// CP0@6176(8000), MA@14176(8000)

#define MS 16
struct P4 { const float* p[4]; };

__device__ __forceinline__ float bitselF(unsigned m, int k, float v) {
    int s = ((int)(m << (31 - k))) >> 31;
    return __int_as_float(s & __float_as_int(v));
}
__device__ __forceinline__ float fbfly(float v) {
#pragma unroll
    for (int o = 32; o; o >>= 1) v += __shfl_xor(v, o);
    return v;
}
__device__ __forceinline__ int ibfly(int v) {
#pragma unroll
    for (int o = 32; o; o >>= 1) v += __shfl_xor(v, o);
    return v;
}
__device__ __forceinline__ float sigm(float x) { return 1.f / (1.f + expf(-x)); }

// wave-cooperative stable-rank over padded 512 array (pads = -1)
__device__ __forceinline__ int wrank(const float* __restrict__ sc, float my,
                                     int r, int lane) {
    int cnt = 0;
#pragma unroll
    for (int q = 0; q < 2; ++q) {
        int j = (lane + 64 * q) << 2;
        float4 v = *(const float4*)(sc + j);
        cnt += (v.x > my) || (v.x == my && (j + 0) < r);
        cnt += (v.y > my) || (v.y == my && (j + 1) < r);
        cnt += (v.z > my) || (v.z == my && (j + 2) < r);
        cnt += (v.w > my) || (v.w == my && (j + 3) < r);
    }
    return ibfly(cnt);
}

// sparse bit-walk over a 16-word LDS row
__device__ __forceinline__ float pwalk16(const unsigned* __restrict__ row,
                                         const float* __restrict__ val) {
    float a = 0.f;
#pragma unroll
    for (int w = 0; w < 16; ++w) {
        unsigned m = row[w];
        while (m) {
            int b = __ffs((int)m) - 1;
            m &= m - 1;
            a += val[(w << 5) + b];
        }
    }
    return a;
}

// K1: V[row] = dot(h[row,:], W_top); MA[row] = bitmask(g row); zero SELA.
__global__ __launch_bounds__(1024) void k_dot(const float* __restrict__ h,
        const float* __restrict__ Wt, const float* __restrict__ g,
        float* __restrict__ V, unsigned* __restrict__ MA,
        unsigned* __restrict__ SELA) {
    int row = blockIdx.x, t = threadIdx.x;
    if (row == 0 && t < 32) SELA[t] = 0u;
    const float4* h4 = (const float4*)(h + (size_t)row * 32768);
    const float4* w4 = (const float4*)Wt;
    float acc = 0.f;
#pragma unroll
    for (int j = 0; j < 8; ++j) {
        float4 a = h4[t + 1024 * j], b = w4[t + 1024 * j];
        acc = fmaf(a.x, b.x, fmaf(a.y, b.y, fmaf(a.z, b.z, fmaf(a.w, b.w, acc))));
    }
    acc = fbfly(acc);
    __shared__ float red[16];
    if ((t & 63) == 0) red[t >> 6] = acc;
    __syncthreads();
    if (t == 0) {
        float s = 0.f;
        for (int i = 0; i < 16; ++i) s += red[i];
        V[row] = s;
    }
    if (t < 512) {
        float gv = (t < 500) ? g[row * 500 + t] : 0.f;
        unsigned long long bal = __ballot(gv != 0.f);
        if ((t & 63) == 0) {
            int w = t >> 6;
            MA[row * MS + 2 * w] = (unsigned)bal;
            MA[row * MS + 2 * w + 1] = (unsigned)(bal >> 32);
        }
    }
}

// K2/K3: wave-per-row masked matvec on sparse g.
// mode 0: y = relu(acc + c0), also out[r]. mode 1: y = relu(acc*c0 + c1).
__global__ __launch_bounds__(256) void k_row(const unsigned* __restrict__ MA,
        const float* __restrict__ x, const float* __restrict__ c0,
        const float* __restrict__ c1, float* __restrict__ y,
        float* __restrict__ out, int mode) {
    __shared__ float sv[512];
    int t = threadIdx.x;
    sv[t] = (t < 500) ? x[t] : 0.f;
    int t2 = t + 256;
    sv[t2] = (t2 < 500) ? x[t2] : 0.f;
    __syncthreads();
    int wid = t >> 6, lane = t & 63;
    int r = blockIdx.x * 4 + wid;
    float acc = 0.f;
#pragma unroll
    for (int j = 0; j < 8; ++j) {
        unsigned m = MA[r * MS + 2 * j + (lane >> 5)];
        acc += bitselF(m, lane & 31, sv[64 * j + lane]);
    }
    acc = fbfly(acc);
    if (lane == 0) {
        if (mode == 0) {
            float hv = fmaxf(acc + c0[0], 0.f);
            out[r] = hv;
            y[r] = hv;
        } else {
            y[r] = fmaxf(acc * c0[0] + c1[0], 0.f);
        }
    }
}

// K4: stable top-400 of Z; writes IDXA, SELA bits, HSo = SH*sigmoid(z).
__global__ __launch_bounds__(256) void k_rank0(const float* __restrict__ Z,
        const float* __restrict__ SHo, int* __restrict__ IDXA,
        unsigned* __restrict__ SELA, float* __restrict__ HSo) {
    __shared__ __align__(16) float sz[512];
    int t = threadIdx.x;
    sz[t] = (t < 500) ? Z[t] : -1.f;
    int t2 = t + 256;
    sz[t2] = (t2 < 500) ? Z[t2] : -1.f;
    __syncthreads();
    int wid = t >> 6, lane = t & 63;
    int r = blockIdx.x * 4 + wid;
    float my = sz[r];
    int cnt = wrank(sz, my, r, lane);
    if (lane == 0 && cnt < 400) {
        IDXA[cnt] = r;
        HSo[r] = SHo[r] * sigm(my);
        atomicOr(&SELA[r >> 5], 1u << (r & 31));
    }
}

// K5: dense 2-hop over sparse g for the 400 selected; emits complement CP0,
// RSUMo, SU (compact+orig). Also zero-pads SUc tail.
__global__ __launch_bounds__(256) void k_hop0(const unsigned* __restrict__ MA,
        const int* __restrict__ IDXA, const unsigned* __restrict__ SELA,
        const float* __restrict__ HSo, const float* __restrict__ Wd0,
        unsigned* __restrict__ CP0, float* __restrict__ RSUMo,
        float* __restrict__ SUc, float* __restrict__ SUo) {
    int t = threadIdx.x, wid = t >> 6, lane = t & 63;
    if (blockIdx.x == 0 && t < 112) SUc[400 + t] = 0.f;
    int r4 = blockIdx.x * 4 + wid;  // < 400
    int i = IDXA[r4];
    __shared__ unsigned sSEL[16], srow[4][16], un2[4][16];
    if (t < 16) sSEL[t] = SELA[t];
    if (lane < 16) {
        srow[wid][lane] = MA[i * MS + lane];
        un2[wid][lane] = 0u;
    }
    __syncthreads();
    int part = lane >> 4, w = lane & 15;
    unsigned acc = 0;
    for (int k = part; k < 500; k += 4) {
        unsigned sel = (srow[wid][k >> 5] >> (k & 31)) & 1u;
        acc |= MA[k * MS + w] & (0u - sel);
    }
    atomicOr(&un2[wid][w], acc);
    __syncthreads();
    if (lane < 16) {
        unsigned P = sSEL[lane] & ~un2[wid][lane];
        CP0[i * MS + lane] = P;
        int pc = __popc(P);
        pc += __shfl_xor(pc, 1);
        pc += __shfl_xor(pc, 2);
        pc += __shfl_xor(pc, 4);
        pc += __shfl_xor(pc, 8);
        if (lane == 0) {
            float rs = (float)(400 - pc);
            RSUMo[i] = rs;
            float su = HSo[i] * Wd0[r4] / rs;
            SUc[r4] = su;
            SUo[i] = su;
        }
    }
}

// K6: layer-0 down-GCN: h1 = relu(total(SU) - complement + bd0).
__global__ __launch_bounds__(256) void k_m0(const int* __restrict__ IDXA,
        const unsigned* __restrict__ CP0, const float* __restrict__ SUc,
        const float* __restrict__ SUo, const float* __restrict__ RSUMo,
        const float* __restrict__ bd0, float* __restrict__ out,
        float* __restrict__ H1c, float* __restrict__ S2c,
        float* __restrict__ S2o) {
    __shared__ float sO[512];
    int t = threadIdx.x, wid = t >> 6, lane = t & 63;
    sO[t] = (t < 500) ? SUo[t] : 0.f;
    int t2 = t + 256;
    sO[t2] = (t2 < 500) ? SUo[t2] : 0.f;
    if (blockIdx.x == 0 && t < 112) S2c[400 + t] = 0.f;
    __syncthreads();
    float a = 0.f;
    {
        float4 v = *(const float4*)(SUc + lane * 4);
        a += (v.x + v.y) + (v.z + v.w);
        float4 u = *(const float4*)(SUc + lane * 4 + 256);
        a += (u.x + u.y) + (u.z + u.w);
    }
    float tot = fbfly(a);
    int r4 = blockIdx.x * 4 + wid;
    int i = IDXA[r4];
    float corr = 0.f;
    if (lane < 16) {
        unsigned m = CP0[i * MS + lane];
        while (m) {
            int b = __ffs((int)m) - 1;
            m &= m - 1;
            corr += sO[lane * 32 + b];
        }
    }
    corr = fbfly(corr);
    if (lane == 0) {
        float h1 = fmaxf(tot - corr + bd0[0], 0.f);
        out[500 + r4] = h1;
        H1c[r4] = h1;
        float s2 = h1 / RSUMo[i];
        S2c[r4] = s2;
        S2o[i] = s2;
    }
}

// K7: layer-1 scores z1 (compact order); pads Z1c tail with -1.
__global__ __launch_bounds__(256) void k_z1(const int* __restrict__ IDXA,
        const unsigned* __restrict__ CP0, const float* __restrict__ S2c,
        const float* __restrict__ S2o, const float* __restrict__ Wp1,
        const float* __restrict__ bp1, float* __restrict__ Z1c) {
    __shared__ float sO[512];
    int t = threadIdx.x, wid = t >> 6, lane = t & 63;
    sO[t] = (t < 500) ? S2o[t] : 0.f;
    int t2 = t + 256;
    sO[t2] = (t2 < 500) ? S2o[t2] : 0.f;
    if (blockIdx.x == 0 && t < 112) Z1c[400 + t] = -1.f;
    __syncthreads();
    float a = 0.f;
    {
        float4 v = *(const float4*)(S2c + lane * 4);
        a += (v.x + v.y) + (v.z + v.w);
        float4 u = *(const float4*)(S2c + lane * 4 + 256);
        a += (u.x + u.y) + (u.z + u.w);
    }
    float tot = fbfly(a);
    int r4 = blockIdx.x * 4 + wid;
    int i = IDXA[r4];
    float corr = 0.f;
    if (lane < 16) {
        unsigned m = CP0[i * MS + lane];
        while (m) {
            int b = __ffs((int)m) - 1;
            m &= m - 1;
            corr += sO[lane * 32 + b];
        }
    }
    corr = fbfly(corr);
    if (lane == 0) Z1c[r4] = fmaxf((tot - corr) * Wp1[0] + bp1[0], 0.f);
}

// K8: rank top-300 + hop1 (early-exit) + scalar cascade (complete-graph fast
// path) or general fallback for layers 1-3.
__global__ __launch_bounds__(1024) void k_fin(const int* __restrict__ IDXA,
        const unsigned* __restrict__ CP0g, const float* __restrict__ Z1cg,
        const float* __restrict__ H1c, const unsigned* __restrict__ SELAg,
        P4 Wp, P4 bp, P4 Wd, P4 bd, float* __restrict__ out) {
    __shared__ unsigned sCP[8000];
    __shared__ __align__(16) float szC[512], svC[512], s2C[512];
    __shared__ float svO[512], s2O[512], shvO[512], sHSo[512], srsO[512];
    __shared__ int sIDXp[2][512];
    __shared__ unsigned sSELp[2][16];
    __shared__ float sS[8];
    __shared__ float stotS;
    __shared__ int sFlag;
    int t = threadIdx.x, wid = t >> 6, lane = t & 63;
    for (int q = t; q < 8000; q += 1024) sCP[q] = CP0g[q];
    if (t < 512) {
        szC[t] = Z1cg[t];  // pads -1 from K7
        sIDXp[0][t] = (t < 400) ? IDXA[t] : 0;
    }
    if (t < 16) {
        sSELp[0][t] = SELAg[t];
        sSELp[1][t] = 0u;
    }
    if (t == 0) sFlag = 0;
    __syncthreads();
    if (t < 400) shvO[sIDXp[0][t]] = H1c[t];
    __syncthreads();
    // rank: top-300 of 400 (compact tie-break)
    for (int r = wid; r < 400; r += 16) {
        float my = szC[r];
        int cnt = wrank(szC, my, r, lane);
        if (lane == 0 && cnt < 300) {
            int io = sIDXp[0][r];
            sIDXp[1][cnt] = io;
            sHSo[io] = shvO[io] * sigm(my);
            atomicOr(&sSELp[1][io >> 5], 1u << (io & 31));
        }
    }
    __syncthreads();
    // hop1: intersect of complements, early exit; set flag if any row nonempty
    unsigned P[16];
    int inew = 0, pc = 0;
    float su_ = 0.f;
    if (t < 300) {
        inew = sIDXp[1][t];
#pragma unroll
        for (int w = 0; w < 16; ++w) P[w] = sSELp[1][w];
        bool alive = true;
        for (int w2 = 0; w2 < 16 && alive; ++w2) {
            unsigned nb = sSELp[0][w2] & ~sCP[inew * MS + w2];
            while (nb) {
                int b = __ffs((int)nb) - 1;
                nb &= nb - 1;
                const unsigned* cj = sCP + (w2 * 32 + b) * MS;
                unsigned orr = 0;
#pragma unroll
                for (int w = 0; w < 16; ++w) {
                    P[w] &= cj[w];
                    orr |= P[w];
                }
                if (!orr) { alive = false; break; }
            }
        }
#pragma unroll
        for (int w = 0; w < 16; ++w) pc += __popc(P[w]);
        if (pc > 0) atomicOr(&sFlag, 1);
        float rs = (float)(300 - pc);
        su_ = sHSo[inew] * Wd.p[1][t] / rs;
    }
    __syncthreads();
    if (t < 300) {
#pragma unroll
        for (int w = 0; w < 16; ++w) sCP[inew * MS + w] = P[w];
        srsO[inew] = (float)(300 - pc);
        svC[t] = su_;
        svO[inew] = su_;
    } else if (t < 512) {
        svC[t] = 0.f;
    }
    __syncthreads();
    if (sFlag == 0) {
        // ---- scalar fast path: layers 1-3 graphs are complete ----
        if (t < 64) {
            float p = 0.f;
#pragma unroll
            for (int j = 0; j < 8; ++j) p += svC[t * 8 + j];
            p = fbfly(p);
            if (t == 0) {
                float h2 = fmaxf(p + bd.p[1][0], 0.f);
                float z2 = fmaxf(h2 * Wp.p[2][0] + bp.p[2][0], 0.f);
                sS[0] = h2;
                sS[1] = h2 * sigm(z2);  // HS2
            }
        }
        __syncthreads();
        float HS2 = sS[1];
        if (t < 512) s2C[t] = (t < 200) ? HS2 * Wd.p[2][t] / 200.f : 0.f;
        __syncthreads();
        if (t < 64) {
            float p = 0.f;
#pragma unroll
            for (int j = 0; j < 8; ++j) p += s2C[t * 8 + j];
            p = fbfly(p);
            if (t == 0) {
                float h3 = fmaxf(p + bd.p[2][0], 0.f);
                float z3 = fmaxf(h3 * Wp.p[3][0] + bp.p[3][0], 0.f);
                sS[2] = h3;
                sS[3] = h3 * sigm(z3);  // HS3
            }
        }
        __syncthreads();
        float HS3 = sS[3];
        if (t < 512) s2C[t] = (t < 100) ? HS3 * Wd.p[3][t] / 100.f : 0.f;
        __syncthreads();
        if (t < 64) {
            float p = 0.f;
#pragma unroll
            for (int j = 0; j < 8; ++j) p += s2C[t * 8 + j];
            p = fbfly(p);
            if (t == 0) sS[4] = fmaxf(p + bd.p[3][0], 0.f);  // h4
        }
        __syncthreads();
        if (t < 300) out[900 + t] = sS[0];
        else if (t < 500) out[1200 + (t - 300)] = sS[2];
        else if (t < 600) out[1400 + (t - 500)] = sS[4];
        return;
    }
    // ---- general fallback (correct; not expected to execute) ----
    const int kks[3] = {300, 200, 100};
    const int kns[3] = {200, 100, 0};
    const int offs[3] = {900, 1200, 1400};
    for (int l = 1; l <= 3; ++l) {
        const int kk = kks[l - 1], knext = kns[l - 1], off = offs[l - 1];
        const int cur = l & 1, nxt = cur ^ 1;
        if (t < 64) {
            float p = 0.f;
#pragma unroll
            for (int j = 0; j < 8; ++j) p += svC[t * 8 + j];
            p = fbfly(p);
            if (t == 0) stotS = p;
        }
        __syncthreads();
        int i_ = 0;
        if (t < kk) {
            i_ = sIDXp[cur][t];
            float corr = pwalk16(sCP + i_ * MS, svO);
            float hv = fmaxf(stotS - corr + bd.p[l][0], 0.f);
            out[off + t] = hv;
            shvO[i_] = hv;
            float s2 = hv / srsO[i_];
            s2C[t] = s2;
            s2O[i_] = s2;
        } else if (t < 512) {
            s2C[t] = 0.f;
        }
        if (l == 3) break;
        __syncthreads();
        if (t < 64) {
            float p = 0.f;
#pragma unroll
            for (int j = 0; j < 8; ++j) p += s2C[t * 8 + j];
            p = fbfly(p);
            if (t == 0) stotS = p;
        }
        if (t < 16) sSELp[nxt][t] = 0u;
        __syncthreads();
        float z_ = -1.f;
        if (t < kk) {
            float c2 = pwalk16(sCP + i_ * MS, s2O);
            z_ = fmaxf((stotS - c2) * Wp.p[l + 1][0] + bp.p[l + 1][0], 0.f);
        }
        if (t < 512) szC[t] = (t < kk) ? z_ : -1.f;
        __syncthreads();
        for (int r = wid; r < kk; r += 16) {
            float my = szC[r];
            int cnt = wrank(szC, my, r, lane);
            if (lane == 0 && cnt < knext) {
                int io = sIDXp[cur][r];
                sIDXp[nxt][cnt] = io;
                sHSo[io] = shvO[io] * sigm(my);
                atomicOr(&sSELp[nxt][io >> 5], 1u << (io & 31));
            }
        }
        __syncthreads();
        unsigned Q[16];
        int in2 = 0, pc2 = 0;
        float su2_ = 0.f;
        if (t < knext) {
            in2 = sIDXp[nxt][t];
#pragma unroll
            for (int w = 0; w < 16; ++w) Q[w] = sSELp[nxt][w];
            bool alive = true;
            for (int w2 = 0; w2 < 16 && alive; ++w2) {
                unsigned nb = sSELp[cur][w2] & ~sCP[in2 * MS + w2];
                while (nb) {
                    int b = __ffs((int)nb) - 1;
                    nb &= nb - 1;
                    const unsigned* cj = sCP + (w2 * 32 + b) * MS;
                    unsigned orr = 0;
#pragma unroll
                    for (int w = 0; w < 16; ++w) {
                        Q[w] &= cj[w];
                        orr |= Q[w];
                    }
                    if (!orr) { alive = false; break; }
                }
            }
#pragma unroll
            for (int w = 0; w < 16; ++w) pc2 += __popc(Q[w]);
            float rs = (float)(knext - pc2);
            su2_ = sHSo[in2] * Wd.p[l + 1][t] / rs;
        }
        __syncthreads();
        if (t < knext) {
#pragma unroll
            for (int w = 0; w < 16; ++w) sCP[in2 * MS + w] = Q[w];
            srsO[in2] = (float)(knext - pc2);
            svC[t] = su2_;
            svO[in2] = su2_;
        } else if (t < 512) {
            svC[t] = 0.f;
        }
        __syncthreads();
    }
}

extern "C" void kernel_launch(void* const* d_in, const int* in_sizes, int n_in,
                              void* d_out, int out_size, void* d_ws, size_t ws_size,
                              hipStream_t stream) {
    const float* g = (const float*)d_in[0];
    const float* h = (const float*)d_in[1];
    const float* W_top = (const float*)d_in[2];
    const float* b_top = (const float*)d_in[3];
    P4 Wp, bp, Wd, bd;
    for (int i = 0; i < 4; ++i) {
        Wp.p[i] = (const float*)d_in[4 + 4 * i];
        bp.p[i] = (const float*)d_in[5 + 4 * i];
        Wd.p[i] = (const float*)d_in[6 + 4 * i];
        bd.p[i] = (const float*)d_in[7 + 4 * i];
    }
    float* out = (float*)d_out;

    unsigned* wsu = (unsigned*)d_ws;
    float* V = (float*)(wsu + 0);
    float* SHo = (float*)(wsu + 512);
    float* Z = (float*)(wsu + 1024);
    int* IDXA = (int*)(wsu + 1536);
    unsigned* SELA = wsu + 2048;
    float* HSo = (float*)(wsu + 2080);
    float* RSUMo = (float*)(wsu + 2592);
    float* SUc = (float*)(wsu + 3104);
    float* SUo = (float*)(wsu + 3616);
    float* H1c = (float*)(wsu + 4128);
    float* S2c = (float*)(wsu + 4640);
    float* S2o = (float*)(wsu + 5152);
    float* Z1c = (float*)(wsu + 5664);
    unsigned* CP0 = wsu + 6176;
    unsigned* MA = wsu + 14176;

    k_dot<<<500, 1024, 0, stream>>>(h, W_top, g, V, MA, SELA);
    k_row<<<125, 256, 0, stream>>>(MA, V, b_top, nullptr, SHo, out, 0);
    k_row<<<125, 256, 0, stream>>>(MA, SHo, Wp.p[0], bp.p[0], Z, nullptr, 1);
    k_rank0<<<125, 256, 0, stream>>>(Z, SHo, IDXA, SELA, HSo);
    k_hop0<<<100, 256, 0, stream>>>(MA, IDXA, SELA, HSo, Wd.p[0], CP0, RSUMo,
                                    SUc, SUo);
    k_m0<<<100, 256, 0, stream>>>(IDXA, CP0, SUc, SUo, RSUMo, bd.p[0], out, H1c,
                                  S2c, S2o);
    k_z1<<<100, 256, 0, stream>>>(IDXA, CP0, S2c, S2o, Wp.p[1], bp.p[1], Z1c);
    k_fin<<<1, 1024, 0, stream>>>(IDXA, CP0, Z1c, H1c, SELA, Wp, bp, Wd, bd, out);
}